// Round 1
// baseline (86.531 us; speedup 1.0000x reference)
//
#include <hip/hip_runtime.h>

// Problem constants (from reference setup_inputs): batch=4, seq=4096, dim=1024, fp32.
#define BATCH 4
#define SEQ   4096
#define DIM   1024
#define DIM4  (DIM / 4)      // 256 float4 lanes across dim
#define NC    128            // number of time chunks
#define CHUNK (SEQ / NC)     // 32 timesteps per chunk

__device__ __forceinline__ float4 f4_fma(float4 a, float4 h, float4 b) {
    float4 r;
    r.x = fmaf(a.x, h.x, b.x);
    r.y = fmaf(a.y, h.y, b.y);
    r.z = fmaf(a.z, h.z, b.z);
    r.w = fmaf(a.w, h.w, b.w);
    return r;
}

__device__ __forceinline__ float4 f4_mul(float4 a, float4 b) {
    float4 r;
    r.x = a.x * b.x;
    r.y = a.y * b.y;
    r.z = a.z * b.z;
    r.w = a.w * b.w;
    return r;
}

// Phase 1: per-(batch, chunk, dim4) summary of the chunk as an affine map
// h_out = P * h_in + Q   (P = prod of a over chunk, Q = local scan with h_in=0)
__global__ __launch_bounds__(256) void ssm_phase1(const float4* __restrict__ A,
                                                  const float4* __restrict__ B,
                                                  float4* __restrict__ P,
                                                  float4* __restrict__ Q) {
    const int c  = blockIdx.x % NC;
    const int b  = blockIdx.x / NC;
    const int d4 = threadIdx.x;   // 0..DIM4-1

    size_t base = ((size_t)b * SEQ + (size_t)c * CHUNK) * DIM4 + d4;

    float4 p = make_float4(1.f, 1.f, 1.f, 1.f);
    float4 q = make_float4(0.f, 0.f, 0.f, 0.f);

#pragma unroll 8
    for (int t = 0; t < CHUNK; ++t) {
        float4 a  = A[base + (size_t)t * DIM4];
        float4 bb = B[base + (size_t)t * DIM4];
        q = f4_fma(a, q, bb);
        p = f4_mul(p, a);
    }

    size_t w = ((size_t)b * NC + c) * DIM4 + d4;
    P[w] = p;
    Q[w] = q;
}

// Phase 2: serial scan over the NC chunk summaries per channel.
// Writes the carry-IN state for each chunk, in place over P.
__global__ __launch_bounds__(256) void ssm_phase2(float4* __restrict__ PH,   // in: P, out: carry-in H
                                                  const float4* __restrict__ Q) {
    const int gid = blockIdx.x * 256 + threadIdx.x;   // 0 .. BATCH*DIM4-1
    const int b   = gid / DIM4;
    const int d4  = gid % DIM4;

    float4 h = make_float4(0.f, 0.f, 0.f, 0.f);
    for (int c = 0; c < NC; ++c) {
        size_t idx = ((size_t)b * NC + c) * DIM4 + d4;
        float4 p = PH[idx];
        float4 q = Q[idx];
        PH[idx] = h;              // carry-in for chunk c (p,q already in registers)
        h = f4_fma(p, h, q);      // carry-out -> carry-in of chunk c+1
    }
}

// Phase 3: re-run the recurrence per chunk seeded with its carry-in; emit y = c * h.
__global__ __launch_bounds__(256) void ssm_phase3(const float4* __restrict__ A,
                                                  const float4* __restrict__ B,
                                                  const float4* __restrict__ C,
                                                  const float4* __restrict__ H,
                                                  float4* __restrict__ Y) {
    const int c  = blockIdx.x % NC;
    const int b  = blockIdx.x / NC;
    const int d4 = threadIdx.x;

    size_t base = ((size_t)b * SEQ + (size_t)c * CHUNK) * DIM4 + d4;

    float4 h = H[((size_t)b * NC + c) * DIM4 + d4];

#pragma unroll 4
    for (int t = 0; t < CHUNK; ++t) {
        float4 a  = A[base + (size_t)t * DIM4];
        float4 bb = B[base + (size_t)t * DIM4];
        float4 cc = C[base + (size_t)t * DIM4];
        h = f4_fma(a, h, bb);
        Y[base + (size_t)t * DIM4] = f4_mul(cc, h);
    }
}

extern "C" void kernel_launch(void* const* d_in, const int* in_sizes, int n_in,
                              void* d_out, int out_size, void* d_ws, size_t ws_size,
                              hipStream_t stream) {
    // setup_inputs order: x (unused), B, C, A — all fp32 [4, 4096, 1024]
    const float* B = (const float*)d_in[1];
    const float* C = (const float*)d_in[2];
    const float* A = (const float*)d_in[3];
    float* Y = (float*)d_out;

    // Workspace: P (reused as carry H) then Q, each BATCH*NC*DIM floats = 2 MB.
    float* P = (float*)d_ws;
    float* Q = P + (size_t)BATCH * NC * DIM;

    ssm_phase1<<<BATCH * NC, 256, 0, stream>>>(
        (const float4*)A, (const float4*)B, (float4*)P, (float4*)Q);

    ssm_phase2<<<(BATCH * DIM4) / 256, 256, 0, stream>>>(
        (float4*)P, (const float4*)Q);

    ssm_phase3<<<BATCH * NC, 256, 0, stream>>>(
        (const float4*)A, (const float4*)B, (const float4*)C,
        (const float4*)P, (float4*)Y);
}